// Round 5
// baseline (288.280 us; speedup 1.0000x reference)
//
#include <hip/hip_runtime.h>
#include <math.h>

// GradLoss over (B=8, C=4, D=64, H=128, W=128) fp32 tensors.
// out = sum over axes {D,H,W} of sum_c mean_{b,d,h,w} (clean(grad(x)) - clean(grad(t)))^2
//
// R5: MLP fix. R4 diagnosis: 257k cyc/CU for 512 wave-iters = ~6000 cyc/iter
// = 6 loads x ~1000 cyc fully serialized -- VGPR_Count=60 forced the compiler
// to reuse the same load registers every iteration (vmcnt(0) chains).
// Fix: __launch_bounds__(256,2) lifts the VGPR cap + explicit depth-2
// rotating prefetch (12 float4 loads in flight per lane = 12 KB/wave
// outstanding) so load issue is decoupled from consumption.

#define Bn 8
#define Cn 4
#define Dn 64
#define Hn 128
#define Wn 128

static constexpr int HCHUNK = 8;             // h-steps per thread
static constexpr int NTHREADS = 256;         // w4(32) x dlow(8)
static constexpr int NBLOCKS = 4096;         // bc(32) x hc(16) x dhigh(8)
static constexpr int ROW = Wn / 4;           // 32 float4 per W-row
static constexpr int PLANE = Hn * ROW;       // 4096 float4 per (H,W) plane

__global__ __launch_bounds__(NTHREADS, 2) void gradloss_main(
        const float* __restrict__ xf, const float* __restrict__ tf,
        double* __restrict__ partials) {
    const int tid  = threadIdx.x;
    const int w4   = tid & 31;          // float4 index within W-row
    const int dlow = tid >> 5;          // 8 consecutive d-planes per block (L1 reuse)
    const int b    = blockIdx.x;
    const int bc    = b & 31;           // low bits -> XCD = bc%8: slab-per-XCD
    const int hc    = (b >> 5) & 15;
    const int dhigh = b >> 9;
    const int d  = dhigh * 8 + dlow;
    const int h0 = hc * HCHUNK;

    const int base = ((bc * Dn + d) * Hn + h0) * ROW + w4;  // float4 index
    const float4* __restrict__ Xr0 = (const float4*)xf + base;
    const float4* __restrict__ Tr0 = (const float4*)tf + base;

    const int dpo = (d < Dn - 1) ? PLANE : 0;
    const int dmo = (d > 0) ? -PLANE : 0;
    const float sd2  = (d == 0 || d == Dn - 1) ? 1.0f : 0.25f;
    const float sw02 = (w4 == 0) ? 1.0f : 0.25f;
    const float sw32 = (w4 == 31) ? 1.0f : 0.25f;

    // -------- depth-2 rotating prefetch buffers (registers) --------
    float4 bxp[2], btp[2], bxdp[2], btdp[2], bxdm[2], btdm[2];

    // u = x - t sliding window: um = u(h-1), uc = u(h)
    float4 uc, um;
    {
        const float4 xc = Xr0[0], tc = Tr0[0];
        uc.x = xc.x - tc.x; uc.y = xc.y - tc.y;
        uc.z = xc.z - tc.z; uc.w = xc.w - tc.w;
    }
    if (h0 > 0) {   // block-uniform branch
        const float4 xm = Xr0[-ROW], tm = Tr0[-ROW];
        um.x = xm.x - tm.x; um.y = xm.y - tm.y;
        um.z = xm.z - tm.z; um.w = xm.w - tm.w;
    } else {
        um = uc;
    }

    // issue the 6 loads for iteration hl into slot s
    auto issue = [&](int hl, int s) {
        const int c  = hl * ROW;
        const int po = (h0 + hl < Hn - 1) ? c + ROW : c;
        bxp[s]  = Xr0[po];      btp[s]  = Tr0[po];
        bxdp[s] = Xr0[c + dpo]; btdp[s] = Tr0[c + dpo];
        bxdm[s] = Xr0[c + dmo]; btdm[s] = Tr0[c + dmo];
    };
    issue(0, 0);
    issue(1, 1);

    float acc0 = 0.0f, acc1 = 0.0f, acc2 = 0.0f;
    #pragma unroll
    for (int hl = 0; hl < HCHUNK; ++hl) {
        const int s = hl & 1;
        // consume this iteration's batch (issued 2 iterations ago)
        const float4 xp  = bxp[s],  tp  = btp[s];
        const float4 xdp = bxdp[s], tdp = btdp[s];
        const float4 xdm = bxdm[s], tdm = btdm[s];
        // refill the slot for iteration hl+2 before computing
        if (hl + 2 < HCHUNK) issue(hl + 2, s);

        const float sh2 = (h0 + hl == 0 || h0 + hl == Hn - 1) ? 1.0f : 0.25f;

        float4 up;
        up.x = xp.x - tp.x; up.y = xp.y - tp.y;
        up.z = xp.z - tp.z; up.w = xp.w - tp.w;

        // ---- H axis: diff = sh*(up - um) ----
        { const float dx = up.x - um.x; acc0 = fmaf(dx * dx, sh2, acc0); }
        { const float dx = up.y - um.y; acc0 = fmaf(dx * dx, sh2, acc0); }
        { const float dx = up.z - um.z; acc0 = fmaf(dx * dx, sh2, acc0); }
        { const float dx = up.w - um.w; acc0 = fmaf(dx * dx, sh2, acc0); }

        // ---- D axis: diff = sd*((xdp-xdm) - (tdp-tdm)) ----
        { const float dx = (xdp.x - xdm.x) - (tdp.x - tdm.x); acc1 = fmaf(dx * dx, sd2, acc1); }
        { const float dx = (xdp.y - xdm.y) - (tdp.y - tdm.y); acc1 = fmaf(dx * dx, sd2, acc1); }
        { const float dx = (xdp.z - xdm.z) - (tdp.z - tdm.z); acc1 = fmaf(dx * dx, sd2, acc1); }
        { const float dx = (xdp.w - xdm.w) - (tdp.w - tdm.w); acc1 = fmaf(dx * dx, sd2, acc1); }

        // ---- W axis: neighbors via shfl on u within 32-lane groups ----
        const float ulw = __shfl_up(uc.w, 1, 32);
        const float urx = __shfl_down(uc.x, 1, 32);
        const float ul = (w4 == 0)  ? uc.x : ulw;
        const float ur = (w4 == 31) ? uc.w : urx;
        { const float dx = uc.y - ul;   acc2 = fmaf(dx * dx, sw02, acc2); }
        { const float dx = uc.z - uc.x; acc2 = fmaf(dx * dx, 0.25f, acc2); }
        { const float dx = uc.w - uc.y; acc2 = fmaf(dx * dx, 0.25f, acc2); }
        { const float dx = ur - uc.z;   acc2 = fmaf(dx * dx, sw32, acc2); }

        // slide window
        um = uc; uc = up;
    }

    float acc = (acc0 + acc1) + acc2;

    // wave (64-lane) reduction
    for (int off = 32; off > 0; off >>= 1)
        acc += __shfl_down(acc, off, 64);

    __shared__ float wsum[NTHREADS / 64];
    const int lane = tid & 63;
    const int wid = tid >> 6;
    if (lane == 0) wsum[wid] = acc;
    __syncthreads();
    if (tid == 0) {
        double bsum = (double)wsum[0] + (double)wsum[1] +
                      (double)wsum[2] + (double)wsum[3];
        partials[blockIdx.x] = bsum;
    }
}

__global__ __launch_bounds__(256) void gradloss_reduce(
        const double* __restrict__ partials, float* __restrict__ out, int n) {
    double a = 0.0;
    for (int i = threadIdx.x; i < n; i += 256) a += partials[i];
    for (int off = 32; off > 0; off >>= 1)
        a += __shfl_down(a, off, 64);
    __shared__ double s[4];
    const int lane = threadIdx.x & 63;
    const int wid = threadIdx.x >> 6;
    if (lane == 0) s[wid] = a;
    __syncthreads();
    if (threadIdx.x == 0) {
        double tot = s[0] + s[1] + s[2] + s[3];
        out[0] = (float)(tot / 8388608.0);  // / (B*D*H*W)
    }
}

extern "C" void kernel_launch(void* const* d_in, const int* in_sizes, int n_in,
                              void* d_out, int out_size, void* d_ws, size_t ws_size,
                              hipStream_t stream) {
    const float* x = (const float*)d_in[0];
    const float* t = (const float*)d_in[1];
    float* out = (float*)d_out;
    double* partials = (double*)d_ws;  // NBLOCKS * 8 B = 32 KiB of d_ws

    gradloss_main<<<NBLOCKS, NTHREADS, 0, stream>>>(x, t, partials);
    gradloss_reduce<<<1, 256, 0, stream>>>(partials, out, NBLOCKS);
}